// Round 1
// baseline (1102.400 us; speedup 1.0000x reference)
//
#include <hip/hip_runtime.h>
#include <math.h>

#define EPSV 1e-5f

// ---------------------------------------------------------------- zero (float4)
__global__ __launch_bounds__(256) void k_zero(float4* p, long long n4) {
  long long i = (long long)blockIdx.x * blockDim.x + threadIdx.x;
  long long stride = (long long)gridDim.x * blockDim.x;
  for (; i < n4; i += stride) p[i] = make_float4(0.f, 0.f, 0.f, 0.f);
}

// ---------------------------------------------------------------- degree count
__global__ __launch_bounds__(256) void k_deg(const int* __restrict__ ei,
                                             float* __restrict__ deg, int E) {
  int e = blockIdx.x * blockDim.x + threadIdx.x;
  if (e < E) unsafeAtomicAdd(&deg[ei[E + e]], 1.f);  // dst = ei[E + e]
}

// ---------------------------------------------------------------- dinv = rsqrt(deg+1)
__global__ __launch_bounds__(256) void k_dinv(float* deg, int N) {
  int i = blockIdx.x * blockDim.x + threadIdx.x;
  if (i < N) deg[i] = rsqrtf(deg[i] + 1.f);
}

// ---------------------------------------------------------------- GEMM: h[N,64] = x[N,K] @ W[K,64]
// wave-per-row; lane owns output column (W column cached in VGPRs);
// x row read via uniform (readfirstlane) addresses -> s_load + v_fmac s,v.
// NOTE: x/h deliberately NOT __restrict__ (layer-2 call is in-place; each row
// is read fully before its own store and no other wave touches it).
template <int K>
__global__ __launch_bounds__(256) void k_gemm(const float* x, const float* __restrict__ W,
                                              float* h, int N) {
  int lane = threadIdx.x & 63;
  int wid = (blockIdx.x * blockDim.x + threadIdx.x) >> 6;
  int nw = (gridDim.x * blockDim.x) >> 6;
  float w[K];
#pragma unroll
  for (int k = 0; k < K; ++k) w[k] = W[k * 64 + lane];
  for (int row = wid; row < N; row += nw) {
    int r = __builtin_amdgcn_readfirstlane(row);
    const float* xr = x + (long long)r * K;
    float acc = 0.f;
#pragma unroll
    for (int k = 0; k < K; ++k) acc = fmaf(xr[k], w[k], acc);
    h[(long long)r * 64 + lane] = acc;
  }
}

// ---------------------------------------------------------------- edge scatter-add
// wave per edge, lane = feature. agg[dst][f] += dinv[s]*dinv[d] * h[src][f]
__global__ __launch_bounds__(256) void k_agg(const int* __restrict__ ei,
                                             const float* __restrict__ dinv,
                                             const float* __restrict__ h,
                                             float* __restrict__ agg, int E) {
  int lane = threadIdx.x & 63;
  int e = (int)(((long long)blockIdx.x * blockDim.x + threadIdx.x) >> 6);
  if (e >= E) return;                       // e is wave-uniform; no divergence
  int eu = __builtin_amdgcn_readfirstlane(e);
  int s = ei[eu];                           // src (s_load)
  int d = ei[E + eu];                       // dst (s_load)
  float nrm = dinv[s] * dinv[d];
  float val = nrm * h[(long long)s * 64 + lane];   // coalesced 256B row read
  unsafeAtomicAdd(&agg[(long long)d * 64 + lane], val);
}

// ---------------------------------------------------------------- fused self-loop + bias + BN + ReLU
// in-place into h; re-zeroes agg for the next layer.
__global__ __launch_bounds__(256) void k_post(float4* h4, float4* a4,
                                              const float* __restrict__ dinv,
                                              const float* __restrict__ b,
                                              const float* __restrict__ g,
                                              const float* __restrict__ be,
                                              const float* __restrict__ m,
                                              const float* __restrict__ v, int N) {
  int i = blockIdx.x * blockDim.x + threadIdx.x;
  if (i >= N * 16) return;                  // 16 float4 per node (64 feats)
  int node = i >> 4;
  int f0 = (i & 15) << 2;
  float di = dinv[node], d2 = di * di;
  float4 a = a4[i];
  float4 hv = h4[i];
  float av[4] = {a.x, a.y, a.z, a.w};
  float hh[4] = {hv.x, hv.y, hv.z, hv.w};
  float r[4];
#pragma unroll
  for (int c = 0; c < 4; ++c) {
    int f = f0 + c;
    float A = g[f] * rsqrtf(v[f] + EPSV);
    float B = be[f] - m[f] * A;
    float val = av[c] + d2 * hh[c] + b[f];
    r[c] = fmaxf(fmaf(val, A, B), 0.f);
  }
  h4[i] = make_float4(r[0], r[1], r[2], r[3]);
  a4[i] = make_float4(0.f, 0.f, 0.f, 0.f);
}

// ---------------------------------------------------------------- fused BN2+ReLU + MLP head + sigmoid
// thread per node; Wc1 staged in LDS (broadcast reads); row/mid in registers.
__global__ __launch_bounds__(256) void k_cls(const float* __restrict__ h,
                                             const float* __restrict__ agg,
                                             const float* __restrict__ dinv,
                                             const float* __restrict__ b2,
                                             const float* __restrict__ g2,
                                             const float* __restrict__ be2,
                                             const float* __restrict__ m2,
                                             const float* __restrict__ v2,
                                             const float* __restrict__ Wc1,
                                             const float* __restrict__ bc1,
                                             const float* __restrict__ Wc2,
                                             const float* __restrict__ bc2,
                                             float* __restrict__ out, int N) {
  __shared__ float sW1[64 * 32];
  __shared__ float sW2[32];
  __shared__ float sb1[32];
  for (int i = threadIdx.x; i < 64 * 32; i += blockDim.x) sW1[i] = Wc1[i];
  if (threadIdx.x < 32) {
    sW2[threadIdx.x] = Wc2[threadIdx.x];
    sb1[threadIdx.x] = bc1[threadIdx.x];
  }
  __syncthreads();
  int node = blockIdx.x * blockDim.x + threadIdx.x;
  if (node >= N) return;
  float di = dinv[node], d2 = di * di;
  const float4* ap = (const float4*)(agg + (long long)node * 64);
  const float4* hp = (const float4*)(h + (long long)node * 64);
  float row[64];
#pragma unroll
  for (int j = 0; j < 16; ++j) {
    float4 a = ap[j];
    float4 hv = hp[j];
    float av[4] = {a.x, a.y, a.z, a.w};
    float hh[4] = {hv.x, hv.y, hv.z, hv.w};
#pragma unroll
    for (int c = 0; c < 4; ++c) {
      int f = j * 4 + c;
      float A = g2[f] * rsqrtf(v2[f] + EPSV);
      float B = be2[f] - m2[f] * A;
      float val = av[c] + d2 * hh[c] + b2[f];
      row[f] = fmaxf(fmaf(val, A, B), 0.f);
    }
  }
  float mid[32];
#pragma unroll
  for (int j = 0; j < 32; ++j) mid[j] = sb1[j];
#pragma unroll
  for (int f = 0; f < 64; ++f) {
    float hf = row[f];
#pragma unroll
    for (int j = 0; j < 32; ++j) mid[j] = fmaf(hf, sW1[f * 32 + j], mid[j]);
  }
  float o = bc2[0];
#pragma unroll
  for (int j = 0; j < 32; ++j) o = fmaf(fmaxf(mid[j], 0.f), sW2[j], o);
  out[node] = 1.f / (1.f + expf(-o));
}

// ---------------------------------------------------------------- launch
extern "C" void kernel_launch(void* const* d_in, const int* in_sizes, int n_in,
                              void* d_out, int out_size, void* d_ws, size_t ws_size,
                              hipStream_t stream) {
  const float* x  = (const float*)d_in[0];
  const int* ei   = (const int*)d_in[1];
  const float* W1 = (const float*)d_in[2];
  const float* b1 = (const float*)d_in[3];
  const float* g1 = (const float*)d_in[4];
  const float* be1 = (const float*)d_in[5];
  const float* m1 = (const float*)d_in[6];
  const float* v1 = (const float*)d_in[7];
  const float* W2 = (const float*)d_in[8];
  const float* b2 = (const float*)d_in[9];
  const float* g2 = (const float*)d_in[10];
  const float* be2 = (const float*)d_in[11];
  const float* m2 = (const float*)d_in[12];
  const float* v2 = (const float*)d_in[13];
  const float* Wc1 = (const float*)d_in[14];
  const float* bc1 = (const float*)d_in[15];
  const float* Wc2 = (const float*)d_in[16];
  const float* bc2 = (const float*)d_in[17];
  float* out = (float*)d_out;

  int N = in_sizes[0] / 128;
  int E = in_sizes[1] / 2;
  int Npad = ((N + 63) / 64) * 64;  // keep 256B alignment for following buffers

  float* ws = (float*)d_ws;
  float* deg  = ws;                         // [N] -> becomes dinv after k_dinv
  float* agg  = ws + Npad;                  // [N*64]
  float* hbuf = agg + (long long)N * 64;    // [N*64]

  // zero deg (+pad) and agg in one contiguous pass
  long long zero4 = ((long long)Npad + (long long)N * 64) / 4;
  k_zero<<<2048, 256, 0, stream>>>((float4*)ws, zero4);

  k_deg<<<(E + 255) / 256, 256, 0, stream>>>(ei, deg, E);
  k_dinv<<<(N + 255) / 256, 256, 0, stream>>>(deg, N);

  // layer 1
  k_gemm<128><<<1024, 256, 0, stream>>>(x, W1, hbuf, N);
  k_agg<<<(E + 3) / 4, 256, 0, stream>>>(ei, deg, hbuf, agg, E);
  k_post<<<(N * 16 + 255) / 256, 256, 0, stream>>>((float4*)hbuf, (float4*)agg, deg,
                                                   b1, g1, be1, m1, v1, N);
  // layer 2 (GEMM in-place, agg was re-zeroed by k_post)
  k_gemm<64><<<1024, 256, 0, stream>>>(hbuf, W2, hbuf, N);
  k_agg<<<(E + 3) / 4, 256, 0, stream>>>(ei, deg, hbuf, agg, E);

  // fused BN2 + ReLU + classifier + sigmoid
  k_cls<<<(N + 255) / 256, 256, 0, stream>>>(hbuf, agg, deg, b2, g2, be2, m2, v2,
                                             Wc1, bc1, Wc2, bc2, out, N);
}

// Round 3
// 585.656 us; speedup vs baseline: 1.8823x; 1.8823x over previous
//
#include <hip/hip_runtime.h>
#include <math.h>

#define EPSV 1e-5f

// ---------------------------------------------------------------- zero (float4, grid-stride)
__global__ __launch_bounds__(256) void k_zero(float4* p, long long n4) {
  long long i = (long long)blockIdx.x * blockDim.x + threadIdx.x;
  long long stride = (long long)gridDim.x * blockDim.x;
  for (; i < n4; i += stride) p[i] = make_float4(0.f, 0.f, 0.f, 0.f);
}

// ---------------------------------------------------------------- in-degree histogram (int)
__global__ __launch_bounds__(256) void k_deg(const int* __restrict__ ei,
                                             int* __restrict__ cnt, int E) {
  int e = blockIdx.x * blockDim.x + threadIdx.x;
  if (e < E) atomicAdd(&cnt[ei[E + e]], 1);  // dst = ei[E + e]
}

// ---------------------------------------------------------------- dinv = rsqrt(deg+1)
__global__ __launch_bounds__(256) void k_dinv(const int* __restrict__ cnt,
                                              float* __restrict__ dinv, int N) {
  int i = blockIdx.x * blockDim.x + threadIdx.x;
  if (i < N) dinv[i] = rsqrtf((float)cnt[i] + 1.f);
}

// ---------------------------------------------------------------- scan step 1: per-1024-chunk sums
__global__ __launch_bounds__(256) void k_bsum(const int* __restrict__ cnt,
                                              int* __restrict__ bsum, int N) {
  int b = blockIdx.x, t = threadIdx.x;
  int base = b << 10;
  int v = 0;
#pragma unroll
  for (int i = 0; i < 4; ++i) {
    int idx = base + t + i * 256;
    if (idx < N) v += cnt[idx];
  }
  __shared__ int s[256];
  s[t] = v;
  __syncthreads();
  for (int off = 128; off > 0; off >>= 1) {
    if (t < off) s[t] += s[t + off];
    __syncthreads();
  }
  if (t == 0) bsum[b] = s[0];
}

// ---------------------------------------------------------------- scan step 2: exclusive scan of chunk sums (1 block)
__global__ __launch_bounds__(256) void k_bscan(int* __restrict__ bsum, int nb,
                                               int* __restrict__ offs_last, int E) {
  int t = threadIdx.x;
  int per = (nb + 255) / 256;
  int lo = t * per, hi = min(lo + per, nb);
  int tot = 0;
  for (int i = lo; i < hi; ++i) tot += bsum[i];
  __shared__ int s[256];
  s[t] = tot;
  __syncthreads();
  for (int off = 1; off < 256; off <<= 1) {
    int u = (t >= off) ? s[t - off] : 0;
    __syncthreads();
    s[t] += u;
    __syncthreads();
  }
  int run = s[t] - tot;  // exclusive base for this thread's range
  for (int i = lo; i < hi; ++i) {
    int v = bsum[i];
    bsum[i] = run;
    run += v;
  }
  if (t == 0) *offs_last = E;  // offs[N] = E
}

// ---------------------------------------------------------------- scan step 3: per-chunk exclusive scan + base; writes offs & cursor
__global__ __launch_bounds__(256) void k_scan3(const int* __restrict__ cnt,
                                               const int* __restrict__ bsum,
                                               int* __restrict__ offs,
                                               int* __restrict__ cursor, int N) {
  int b = blockIdx.x, t = threadIdx.x;
  int base = (b << 10) + t * 4;
  int c[4];
  int tot = 0;
#pragma unroll
  for (int i = 0; i < 4; ++i) {
    int idx = base + i;
    c[i] = (idx < N) ? cnt[idx] : 0;
    tot += c[i];
  }
  __shared__ int s[256];
  s[t] = tot;
  __syncthreads();
  for (int off = 1; off < 256; off <<= 1) {
    int u = (t >= off) ? s[t - off] : 0;
    __syncthreads();
    s[t] += u;
    __syncthreads();
  }
  int run = s[t] - tot + bsum[b];
#pragma unroll
  for (int i = 0; i < 4; ++i) {
    int idx = base + i;
    if (idx < N) {
      offs[idx] = run;
      cursor[idx] = run;
      run += c[i];
    }
  }
}

// ---------------------------------------------------------------- CSR edge scatter
__global__ __launch_bounds__(256) void k_scatter(const int* __restrict__ ei,
                                                 int* __restrict__ cursor,
                                                 int* __restrict__ csr, int E) {
  int e = blockIdx.x * blockDim.x + threadIdx.x;
  if (e < E) {
    int s = ei[e];
    int d = ei[E + e];
    int pos = atomicAdd(&cursor[d], 1);
    csr[pos] = s;
  }
}

// ---------------------------------------------------------------- GEMM: out[N,64] = in[N,K] @ W[K,64]
// wave-per-row; lane owns output column (W column in VGPRs);
// input row read via uniform (readfirstlane) addresses -> s_load + v_fmac.
template <int K>
__global__ __launch_bounds__(256) void k_gemm(const float* __restrict__ x,
                                              const float* __restrict__ W,
                                              float* __restrict__ h, int N) {
  int lane = threadIdx.x & 63;
  int wid = (blockIdx.x * blockDim.x + threadIdx.x) >> 6;
  int nw = (gridDim.x * blockDim.x) >> 6;
  float w[K];
#pragma unroll
  for (int k = 0; k < K; ++k) w[k] = W[k * 64 + lane];
  for (int row = wid; row < N; row += nw) {
    int r = __builtin_amdgcn_readfirstlane(row);
    const float* xr = x + (long long)r * K;
    float acc = 0.f;
#pragma unroll
    for (int k = 0; k < K; ++k) acc = fmaf(xr[k], w[k], acc);
    h[(long long)r * 64 + lane] = acc;
  }
}

// ---------------------------------------------------------------- CSR gather + self-loop + bias + BN + ReLU (fused)
// wave per node, lane = feature.
// hout[d] = relu(BN(dinv_d*(sum_s dinv_s*h_s + dinv_d*h_d) + b))
__global__ __launch_bounds__(256) void k_gath(const int* __restrict__ csr,
                                              const int* __restrict__ offs,
                                              const float* __restrict__ dinv,
                                              const float* __restrict__ hin,
                                              const float* __restrict__ b,
                                              const float* __restrict__ g,
                                              const float* __restrict__ be,
                                              const float* __restrict__ m,
                                              const float* __restrict__ v,
                                              float* __restrict__ hout, int N) {
  int lane = threadIdx.x & 63;
  int node = (int)(((long long)blockIdx.x * blockDim.x + threadIdx.x) >> 6);
  if (node >= N) return;                          // wave-uniform
  node = __builtin_amdgcn_readfirstlane(node);
  int beg = offs[node], end = offs[node + 1];
  float acc = 0.f;
  int j = beg;
  for (; j + 4 <= end; j += 4) {                  // 4 independent row loads in flight
    int s0 = csr[j], s1 = csr[j + 1], s2 = csr[j + 2], s3 = csr[j + 3];
    float w0 = dinv[s0], w1 = dinv[s1], w2 = dinv[s2], w3 = dinv[s3];
    float h0 = hin[(long long)s0 * 64 + lane];
    float h1 = hin[(long long)s1 * 64 + lane];
    float h2 = hin[(long long)s2 * 64 + lane];
    float h3 = hin[(long long)s3 * 64 + lane];
    acc = fmaf(w0, h0, acc);
    acc = fmaf(w1, h1, acc);
    acc = fmaf(w2, h2, acc);
    acc = fmaf(w3, h3, acc);
  }
  for (; j < end; ++j) {
    int s = csr[j];
    acc = fmaf(dinv[s], hin[(long long)s * 64 + lane], acc);
  }
  float di = dinv[node];
  acc = fmaf(di, hin[(long long)node * 64 + lane], acc);  // self-loop term
  acc = fmaf(di, acc, b[lane]);                           // single di scale + bias
  float A = g[lane] * rsqrtf(v[lane] + EPSV);
  float B = be[lane] - m[lane] * A;
  hout[(long long)node * 64 + lane] = fmaxf(fmaf(acc, A, B), 0.f);
}

// ---------------------------------------------------------------- MLP head + sigmoid (input already BN+ReLU)
__global__ __launch_bounds__(256) void k_cls(const float* __restrict__ h,
                                             const float* __restrict__ Wc1,
                                             const float* __restrict__ bc1,
                                             const float* __restrict__ Wc2,
                                             const float* __restrict__ bc2,
                                             float* __restrict__ out, int N) {
  __shared__ float sW1[64 * 32];
  __shared__ float sW2[32];
  __shared__ float sb1[32];
  for (int i = threadIdx.x; i < 64 * 32; i += blockDim.x) sW1[i] = Wc1[i];
  if (threadIdx.x < 32) {
    sW2[threadIdx.x] = Wc2[threadIdx.x];
    sb1[threadIdx.x] = bc1[threadIdx.x];
  }
  __syncthreads();
  int node = blockIdx.x * blockDim.x + threadIdx.x;
  if (node >= N) return;
  const float4* hp = (const float4*)(h + (long long)node * 64);
  float mid[32];
#pragma unroll
  for (int j = 0; j < 32; ++j) mid[j] = sb1[j];
#pragma unroll
  for (int j4 = 0; j4 < 16; ++j4) {
    float4 hv = hp[j4];
    float hh[4] = {hv.x, hv.y, hv.z, hv.w};
#pragma unroll
    for (int c = 0; c < 4; ++c) {
      float hf = hh[c];
      int f = j4 * 4 + c;
#pragma unroll
      for (int j = 0; j < 32; ++j) mid[j] = fmaf(hf, sW1[f * 32 + j], mid[j]);
    }
  }
  float o = bc2[0];
#pragma unroll
  for (int j = 0; j < 32; ++j) o = fmaf(fmaxf(mid[j], 0.f), sW2[j], o);
  out[node] = 1.f / (1.f + expf(-o));
}

// ---------------------------------------------------------------- launch
extern "C" void kernel_launch(void* const* d_in, const int* in_sizes, int n_in,
                              void* d_out, int out_size, void* d_ws, size_t ws_size,
                              hipStream_t stream) {
  const float* x  = (const float*)d_in[0];
  const int* ei   = (const int*)d_in[1];
  const float* W1 = (const float*)d_in[2];
  const float* b1 = (const float*)d_in[3];
  const float* g1 = (const float*)d_in[4];
  const float* be1 = (const float*)d_in[5];
  const float* m1 = (const float*)d_in[6];
  const float* v1 = (const float*)d_in[7];
  const float* W2 = (const float*)d_in[8];
  const float* b2 = (const float*)d_in[9];
  const float* g2 = (const float*)d_in[10];
  const float* be2 = (const float*)d_in[11];
  const float* m2 = (const float*)d_in[12];
  const float* v2 = (const float*)d_in[13];
  const float* Wc1 = (const float*)d_in[14];
  const float* bc1 = (const float*)d_in[15];
  const float* Wc2 = (const float*)d_in[16];
  const float* bc2 = (const float*)d_in[17];
  float* out = (float*)d_out;

  int N = in_sizes[0] / 128;
  int E = in_sizes[1] / 2;
  int Npad = ((N + 63) / 64) * 64;
  int nb = (N + 1023) / 1024;  // scan chunks of 1024

  float* ws = (float*)d_ws;
  float* bufA  = ws;                              // [N*64]
  float* bufB  = bufA + (long long)N * 64;        // [N*64]
  int*   csr   = (int*)(bufB + (long long)N * 64);// [E]
  float* dinv  = (float*)(csr + E);               // [Npad]
  int*   cnt   = (int*)(dinv + Npad);             // [Npad]
  int*   offs  = cnt + Npad;                      // [Npad + 64] (need N+1)
  int*   cursor= offs + Npad + 64;                // [Npad]
  int*   bsum  = cursor + Npad;                   // [256+]
  size_t need = (size_t)((char*)(bsum + 512) - (char*)d_ws);
  if (need > ws_size) return;  // fail loudly (wrong output) rather than corrupt

  // ---- graph preprocessing (CSR build) ----
  k_zero<<<256, 256, 0, stream>>>((float4*)cnt, Npad / 4);
  k_deg<<<(E + 255) / 256, 256, 0, stream>>>(ei, cnt, E);
  k_dinv<<<(N + 255) / 256, 256, 0, stream>>>(cnt, dinv, N);
  k_bsum<<<nb, 256, 0, stream>>>(cnt, bsum, N);
  k_bscan<<<1, 256, 0, stream>>>(bsum, nb, offs + N, E);
  k_scan3<<<nb, 256, 0, stream>>>(cnt, bsum, offs, cursor, N);
  k_scatter<<<(E + 255) / 256, 256, 0, stream>>>(ei, cursor, csr, E);

  // ---- layer 1 ----
  k_gemm<128><<<1024, 256, 0, stream>>>(x, W1, bufA, N);
  k_gath<<<(N * 64 + 255) / 256, 256, 0, stream>>>(csr, offs, dinv, bufA,
                                                   b1, g1, be1, m1, v1, bufB, N);
  // ---- layer 2 ----
  k_gemm<64><<<1024, 256, 0, stream>>>(bufB, W2, bufA, N);
  k_gath<<<(N * 64 + 255) / 256, 256, 0, stream>>>(csr, offs, dinv, bufA,
                                                   b2, g2, be2, m2, v2, bufB, N);
  // ---- classifier head ----
  k_cls<<<(N + 255) / 256, 256, 0, stream>>>(bufB, Wc1, bc1, Wc2, bc2, out, N);
}

// Round 4
// 544.602 us; speedup vs baseline: 2.0242x; 1.0754x over previous
//
#include <hip/hip_runtime.h>
#include <math.h>

#define EPSV 1e-5f

typedef _Float16 h16;

static __device__ __forceinline__ float h2f(unsigned int u16) {
  unsigned short s = (unsigned short)u16;
  h16 h;
  __builtin_memcpy(&h, &s, 2);
  return (float)h;
}

// ---------------------------------------------------------------- zero (int4)
__global__ __launch_bounds__(256) void k_zero(int4* p, long long n4) {
  long long i = (long long)blockIdx.x * blockDim.x + threadIdx.x;
  long long stride = (long long)gridDim.x * blockDim.x;
  for (; i < n4; i += stride) p[i] = make_int4(0, 0, 0, 0);
}

// ---------------------------------------------------------------- in-degree histogram (int)
__global__ __launch_bounds__(256) void k_deg(const int* __restrict__ ei,
                                             int* __restrict__ cnt, int E) {
  int e = blockIdx.x * blockDim.x + threadIdx.x;
  if (e < E) atomicAdd(&cnt[ei[E + e]], 1);  // dst row
}

// ---------------------------------------------------------------- scan step 1: per-1024-chunk sums
__global__ __launch_bounds__(256) void k_bsum(const int* __restrict__ cnt,
                                              int* __restrict__ bsum, int N) {
  int b = blockIdx.x, t = threadIdx.x;
  int base = b << 10;
  int v = 0;
#pragma unroll
  for (int i = 0; i < 4; ++i) {
    int idx = base + t + i * 256;
    if (idx < N) v += cnt[idx];
  }
  __shared__ int s[256];
  s[t] = v;
  __syncthreads();
  for (int off = 128; off > 0; off >>= 1) {
    if (t < off) s[t] += s[t + off];
    __syncthreads();
  }
  if (t == 0) bsum[b] = s[0];
}

// ---------------------------------------------------------------- scan step 2: exclusive scan of chunk sums (1 block)
__global__ __launch_bounds__(256) void k_bscan(int* __restrict__ bsum, int nb,
                                               int* __restrict__ offs_last, int E) {
  int t = threadIdx.x;
  int per = (nb + 255) / 256;
  int lo = t * per, hi = min(lo + per, nb);
  int tot = 0;
  for (int i = lo; i < hi; ++i) tot += bsum[i];
  __shared__ int s[256];
  s[t] = tot;
  __syncthreads();
  for (int off = 1; off < 256; off <<= 1) {
    int u = (t >= off) ? s[t - off] : 0;
    __syncthreads();
    s[t] += u;
    __syncthreads();
  }
  int run = s[t] - tot;
  for (int i = lo; i < hi; ++i) {
    int v = bsum[i];
    bsum[i] = run;
    run += v;
  }
  if (t == 0) *offs_last = E;  // offs[N] = E
}

// ---------------------------------------------------------------- scan step 3: per-chunk exclusive scan + base; offs, cursor, dinv
__global__ __launch_bounds__(256) void k_scan3(const int* __restrict__ cnt,
                                               const int* __restrict__ bsum,
                                               int* __restrict__ offs,
                                               int* __restrict__ cursor,
                                               float* __restrict__ dinv, int N) {
  int b = blockIdx.x, t = threadIdx.x;
  int base = (b << 10) + t * 4;
  int c[4];
  int tot = 0;
#pragma unroll
  for (int i = 0; i < 4; ++i) {
    int idx = base + i;
    c[i] = (idx < N) ? cnt[idx] : 0;
    tot += c[i];
  }
  __shared__ int s[256];
  s[t] = tot;
  __syncthreads();
  for (int off = 1; off < 256; off <<= 1) {
    int u = (t >= off) ? s[t - off] : 0;
    __syncthreads();
    s[t] += u;
    __syncthreads();
  }
  int run = s[t] - tot + bsum[b];
#pragma unroll
  for (int i = 0; i < 4; ++i) {
    int idx = base + i;
    if (idx < N) {
      offs[idx] = run;
      cursor[idx] = run;
      dinv[idx] = rsqrtf((float)c[i] + 1.f);
      run += c[i];
    }
  }
}

// ---------------------------------------------------------------- CSR edge scatter, dst-windowed pass
// Only edges with dst in [lo,hi) are written; keeps the csr write window
// ~1MB so 64B lines fill up in cache before writeback (kills partial-line WB).
__global__ __launch_bounds__(256) void k_scat(const int* __restrict__ ei,
                                              int* __restrict__ cursor,
                                              int* __restrict__ csr, int E,
                                              int lo, int hi) {
  int e = blockIdx.x * blockDim.x + threadIdx.x;
  if (e >= E) return;
  int d = ei[E + e];
  if (d < lo || d >= hi) return;
  int s = ei[e];
  int pos = atomicAdd(&cursor[d], 1);
  csr[pos] = s;
}

// ---------------------------------------------------------------- GEMM1: h[N,64](fp16) = x[N,128](fp32) @ W[128,64]
// wave-per-row; lane owns output column (W column in VGPRs);
// x row read via uniform (readfirstlane) addresses -> s_load + v_fmac.
__global__ __launch_bounds__(256) void k_gemm1(const float* __restrict__ x,
                                               const float* __restrict__ W,
                                               h16* __restrict__ h, int N) {
  int lane = threadIdx.x & 63;
  int wid = (blockIdx.x * blockDim.x + threadIdx.x) >> 6;
  int nw = (gridDim.x * blockDim.x) >> 6;
  float w[128];
#pragma unroll
  for (int k = 0; k < 128; ++k) w[k] = W[k * 64 + lane];
  for (int row = wid; row < N; row += nw) {
    int r = __builtin_amdgcn_readfirstlane(row);
    const float* xr = x + (long long)r * 128;
    float acc = 0.f;
#pragma unroll
    for (int k = 0; k < 128; ++k) acc = fmaf(xr[k], w[k], acc);
    h[(long long)r * 64 + lane] = (h16)acc;
  }
}

// ---------------------------------------------------------------- GEMM2: h[N,64](fp16) = in[N,64](fp16) @ W[64,64]
__global__ __launch_bounds__(256) void k_gemm2(const h16* __restrict__ x,
                                               const float* __restrict__ W,
                                               h16* __restrict__ h, int N) {
  int lane = threadIdx.x & 63;
  int wid = (blockIdx.x * blockDim.x + threadIdx.x) >> 6;
  int nw = (gridDim.x * blockDim.x) >> 6;
  float w[64];
#pragma unroll
  for (int k = 0; k < 64; ++k) w[k] = W[k * 64 + lane];
  for (int row = wid; row < N; row += nw) {
    int r = __builtin_amdgcn_readfirstlane(row);
    const unsigned int* xr = (const unsigned int*)(x + (long long)r * 64);
    float acc = 0.f;
#pragma unroll
    for (int k = 0; k < 32; ++k) {
      unsigned int p = xr[k];
      acc = fmaf(h2f(p & 0xffffu), w[2 * k], acc);
      acc = fmaf(h2f(p >> 16), w[2 * k + 1], acc);
    }
    h[(long long)r * 64 + lane] = (h16)acc;
  }
}

// ---------------------------------------------------------------- CSR gather + self-loop + bias + BN + ReLU (fused, fp16 h)
// wave per node, lane = feature.
__global__ __launch_bounds__(256) void k_gath(const int* __restrict__ csr,
                                              const int* __restrict__ offs,
                                              const float* __restrict__ dinv,
                                              const h16* __restrict__ hin,
                                              const float* __restrict__ b,
                                              const float* __restrict__ g,
                                              const float* __restrict__ be,
                                              const float* __restrict__ m,
                                              const float* __restrict__ v,
                                              h16* __restrict__ hout, int N) {
  int lane = threadIdx.x & 63;
  int node = (int)(((long long)blockIdx.x * blockDim.x + threadIdx.x) >> 6);
  if (node >= N) return;
  node = __builtin_amdgcn_readfirstlane(node);
  int beg = offs[node], end = offs[node + 1];
  float acc = 0.f;
  int j = beg;
  for (; j + 4 <= end; j += 4) {  // 4 independent row loads in flight
    int s0 = csr[j], s1 = csr[j + 1], s2 = csr[j + 2], s3 = csr[j + 3];
    float w0 = dinv[s0], w1 = dinv[s1], w2 = dinv[s2], w3 = dinv[s3];
    float h0 = (float)hin[(long long)s0 * 64 + lane];
    float h1 = (float)hin[(long long)s1 * 64 + lane];
    float h2 = (float)hin[(long long)s2 * 64 + lane];
    float h3 = (float)hin[(long long)s3 * 64 + lane];
    acc = fmaf(w0, h0, acc);
    acc = fmaf(w1, h1, acc);
    acc = fmaf(w2, h2, acc);
    acc = fmaf(w3, h3, acc);
  }
  for (; j < end; ++j) {
    int s = csr[j];
    acc = fmaf(dinv[s], (float)hin[(long long)s * 64 + lane], acc);
  }
  float di = dinv[node];
  acc = fmaf(di, (float)hin[(long long)node * 64 + lane], acc);  // self-loop
  acc = fmaf(di, acc, b[lane]);                                  // scale + bias
  float A = g[lane] * rsqrtf(v[lane] + EPSV);
  float B = be[lane] - m[lane] * A;
  hout[(long long)node * 64 + lane] = (h16)fmaxf(fmaf(acc, A, B), 0.f);
}

// ---------------------------------------------------------------- MLP head + sigmoid (fp16 input, already BN+ReLU)
__global__ __launch_bounds__(256) void k_cls(const h16* __restrict__ h,
                                             const float* __restrict__ Wc1,
                                             const float* __restrict__ bc1,
                                             const float* __restrict__ Wc2,
                                             const float* __restrict__ bc2,
                                             float* __restrict__ out, int N) {
  __shared__ float sW1[64 * 32];
  __shared__ float sW2[32];
  __shared__ float sb1[32];
  for (int i = threadIdx.x; i < 64 * 32; i += blockDim.x) sW1[i] = Wc1[i];
  if (threadIdx.x < 32) {
    sW2[threadIdx.x] = Wc2[threadIdx.x];
    sb1[threadIdx.x] = bc1[threadIdx.x];
  }
  __syncthreads();
  int node = blockIdx.x * blockDim.x + threadIdx.x;
  if (node >= N) return;
  const uint4* hp = (const uint4*)(h + (long long)node * 64);
  float mid[32];
#pragma unroll
  for (int j = 0; j < 32; ++j) mid[j] = sb1[j];
#pragma unroll
  for (int j4 = 0; j4 < 8; ++j4) {  // 8 halves per uint4
    uint4 q = hp[j4];
    unsigned int pk[4] = {q.x, q.y, q.z, q.w};
#pragma unroll
    for (int c = 0; c < 4; ++c) {
      float f0 = h2f(pk[c] & 0xffffu);
      float f1 = h2f(pk[c] >> 16);
      int f = j4 * 8 + c * 2;
#pragma unroll
      for (int j = 0; j < 32; ++j) mid[j] = fmaf(f0, sW1[f * 32 + j], mid[j]);
#pragma unroll
      for (int j = 0; j < 32; ++j) mid[j] = fmaf(f1, sW1[(f + 1) * 32 + j], mid[j]);
    }
  }
  float o = bc2[0];
#pragma unroll
  for (int j = 0; j < 32; ++j) o = fmaf(fmaxf(mid[j], 0.f), sW2[j], o);
  out[node] = 1.f / (1.f + expf(-o));
}

// ---------------------------------------------------------------- launch
extern "C" void kernel_launch(void* const* d_in, const int* in_sizes, int n_in,
                              void* d_out, int out_size, void* d_ws, size_t ws_size,
                              hipStream_t stream) {
  const float* x  = (const float*)d_in[0];
  const int* ei   = (const int*)d_in[1];
  const float* W1 = (const float*)d_in[2];
  const float* b1 = (const float*)d_in[3];
  const float* g1 = (const float*)d_in[4];
  const float* be1 = (const float*)d_in[5];
  const float* m1 = (const float*)d_in[6];
  const float* v1 = (const float*)d_in[7];
  const float* W2 = (const float*)d_in[8];
  const float* b2 = (const float*)d_in[9];
  const float* g2 = (const float*)d_in[10];
  const float* be2 = (const float*)d_in[11];
  const float* m2 = (const float*)d_in[12];
  const float* v2 = (const float*)d_in[13];
  const float* Wc1 = (const float*)d_in[14];
  const float* bc1 = (const float*)d_in[15];
  const float* Wc2 = (const float*)d_in[16];
  const float* bc2 = (const float*)d_in[17];
  float* out = (float*)d_out;

  int N = in_sizes[0] / 128;
  int E = in_sizes[1] / 2;
  int Npad = ((N + 63) / 64) * 64;
  int nb = (N + 1023) / 1024;

  char* ws = (char*)d_ws;
  h16*   bufA  = (h16*)ws;                              // [N*64] fp16
  h16*   bufB  = bufA + (long long)N * 64;              // [N*64] fp16
  int*   csr   = (int*)(bufB + (long long)N * 64);      // [E]
  float* dinv  = (float*)(csr + E);                     // [Npad]
  int*   cnt   = (int*)(dinv + Npad);                   // [Npad]
  int*   offs  = cnt + Npad;                            // [Npad + 64]
  int*   cursor = offs + Npad + 64;                     // [Npad]
  int*   bsum  = cursor + Npad;                         // [512]
  size_t need = (size_t)((char*)(bsum + 512) - (char*)d_ws);
  if (need > ws_size) return;  // fail loudly rather than corrupt

  // ---- graph preprocessing (CSR build) ----
  k_zero<<<256, 256, 0, stream>>>((int4*)cnt, Npad / 4);
  k_deg<<<(E + 255) / 256, 256, 0, stream>>>(ei, cnt, E);
  k_bsum<<<nb, 256, 0, stream>>>(cnt, bsum, N);
  k_bscan<<<1, 256, 0, stream>>>(bsum, nb, offs + N, E);
  k_scan3<<<nb, 256, 0, stream>>>(cnt, bsum, offs, cursor, dinv, N);
  // dst-windowed scatter: 16384 nodes (~1MB csr window) per pass
  for (int lo = 0; lo < N; lo += 16384)
    k_scat<<<(E + 255) / 256, 256, 0, stream>>>(ei, cursor, csr, E, lo, lo + 16384);

  // ---- layer 1 ----
  k_gemm1<<<1024, 256, 0, stream>>>(x, W1, bufA, N);
  k_gath<<<(N * 64 + 255) / 256, 256, 0, stream>>>(csr, offs, dinv, bufA,
                                                   b1, g1, be1, m1, v1, bufB, N);
  // ---- layer 2 ----
  k_gemm2<<<1024, 256, 0, stream>>>(bufB, W2, bufA, N);
  k_gath<<<(N * 64 + 255) / 256, 256, 0, stream>>>(csr, offs, dinv, bufA,
                                                   b2, g2, be2, m2, v2, bufB, N);
  // ---- classifier head ----
  k_cls<<<(N + 255) / 256, 256, 0, stream>>>(bufB, Wc1, bc1, Wc2, bc2, out, N);
}

// Round 5
// 465.030 us; speedup vs baseline: 2.3706x; 1.1711x over previous
//
#include <hip/hip_runtime.h>
#include <math.h>

#define EPSV 1e-5f

typedef _Float16 h16;
typedef _Float16 half8 __attribute__((ext_vector_type(8)));
typedef float f32x4 __attribute__((ext_vector_type(4)));

static __device__ __forceinline__ float h2f(unsigned int u16) {
  unsigned short s = (unsigned short)u16;
  h16 h;
  __builtin_memcpy(&h, &s, 2);
  return (float)h;
}

// ---------------------------------------------------------------- zero (int4)
__global__ __launch_bounds__(256) void k_zero(int4* p, long long n4) {
  long long i = (long long)blockIdx.x * blockDim.x + threadIdx.x;
  long long stride = (long long)gridDim.x * blockDim.x;
  for (; i < n4; i += stride) p[i] = make_int4(0, 0, 0, 0);
}

// ---------------------------------------------------------------- in-degree histogram (int)
__global__ __launch_bounds__(256) void k_deg(const int* __restrict__ ei,
                                             int* __restrict__ cnt, int E) {
  int e = blockIdx.x * blockDim.x + threadIdx.x;
  if (e < E) atomicAdd(&cnt[ei[E + e]], 1);  // dst row
}

// ---------------------------------------------------------------- scan step 1: per-1024-chunk sums
__global__ __launch_bounds__(256) void k_bsum(const int* __restrict__ cnt,
                                              int* __restrict__ bsum, int N) {
  int b = blockIdx.x, t = threadIdx.x;
  int base = b << 10;
  int v = 0;
#pragma unroll
  for (int i = 0; i < 4; ++i) {
    int idx = base + t + i * 256;
    if (idx < N) v += cnt[idx];
  }
  __shared__ int s[256];
  s[t] = v;
  __syncthreads();
  for (int off = 128; off > 0; off >>= 1) {
    if (t < off) s[t] += s[t + off];
    __syncthreads();
  }
  if (t == 0) bsum[b] = s[0];
}

// ---------------------------------------------------------------- scan step 2: exclusive scan of chunk sums (1 block)
__global__ __launch_bounds__(256) void k_bscan(int* __restrict__ bsum, int nb,
                                               int* __restrict__ offs_last, int E) {
  int t = threadIdx.x;
  int per = (nb + 255) / 256;
  int lo = t * per, hi = min(lo + per, nb);
  int tot = 0;
  for (int i = lo; i < hi; ++i) tot += bsum[i];
  __shared__ int s[256];
  s[t] = tot;
  __syncthreads();
  for (int off = 1; off < 256; off <<= 1) {
    int u = (t >= off) ? s[t - off] : 0;
    __syncthreads();
    s[t] += u;
    __syncthreads();
  }
  int run = s[t] - tot;
  for (int i = lo; i < hi; ++i) {
    int v = bsum[i];
    bsum[i] = run;
    run += v;
  }
  if (t == 0) *offs_last = E;  // offs[N] = E
}

// ---------------------------------------------------------------- scan step 3: per-chunk exclusive scan + base; offs, cursor, dinv
__global__ __launch_bounds__(256) void k_scan3(const int* __restrict__ cnt,
                                               const int* __restrict__ bsum,
                                               int* __restrict__ offs,
                                               int* __restrict__ cursor,
                                               float* __restrict__ dinv, int N) {
  int b = blockIdx.x, t = threadIdx.x;
  int base = (b << 10) + t * 4;
  int c[4];
  int tot = 0;
#pragma unroll
  for (int i = 0; i < 4; ++i) {
    int idx = base + i;
    c[i] = (idx < N) ? cnt[idx] : 0;
    tot += c[i];
  }
  __shared__ int s[256];
  s[t] = tot;
  __syncthreads();
  for (int off = 1; off < 256; off <<= 1) {
    int u = (t >= off) ? s[t - off] : 0;
    __syncthreads();
    s[t] += u;
    __syncthreads();
  }
  int run = s[t] - tot + bsum[b];
#pragma unroll
  for (int i = 0; i < 4; ++i) {
    int idx = base + i;
    if (idx < N) {
      offs[idx] = run;
      cursor[idx] = run;
      dinv[idx] = rsqrtf((float)c[i] + 1.f);
      run += c[i];
    }
  }
}

// ---------------------------------------------------------------- CSR edge scatter, dst-windowed pass
__global__ __launch_bounds__(256) void k_scat(const int* __restrict__ ei,
                                              int* __restrict__ cursor,
                                              int* __restrict__ csr, int E,
                                              int lo, int hi) {
  int e = blockIdx.x * blockDim.x + threadIdx.x;
  if (e >= E) return;
  int d = ei[E + e];
  if (d < lo || d >= hi) return;
  int s = ei[e];
  int pos = atomicAdd(&cursor[d], 1);
  csr[pos] = s;
}

// ---------------------------------------------------------------- GEMM1 (MFMA): h[N,64](f16) = x[N,128](f32) @ W[128,64](f32)
// 4 waves/block; wave computes 32 rows x 64 cols via 16x16x32 f16 MFMA.
// A: row=lane&15, k=(lane>>4)*8+j ; B: col=lane&15, same k ;
// D: col=lane&15, row=(lane>>4)*4+reg   [m89/m91-verified layouts]
__global__ __launch_bounds__(256, 1) void k_gemm1(const float* __restrict__ x,
                                                  const float* __restrict__ W,
                                                  h16* __restrict__ h, int N) {
  int lane = threadIdx.x & 63;
  int wave = threadIdx.x >> 6;
  int q = lane >> 4, r16 = lane & 15;
  half8 bf[4][4];  // [n_tile][k_step], W is L2-resident
#pragma unroll
  for (int t = 0; t < 4; ++t)
#pragma unroll
    for (int s = 0; s < 4; ++s) {
      const float* wp = W + (s * 32 + q * 8) * 64 + t * 16 + r16;
#pragma unroll
      for (int j = 0; j < 8; ++j) bf[t][s][j] = (h16)wp[j * 64];
    }
  long long base_row = (long long)blockIdx.x * 128 + wave * 32;
#pragma unroll
  for (int rt = 0; rt < 2; ++rt) {
    long long row0 = base_row + rt * 16;
    long long arow = row0 + r16;
    if (arow >= N) arow = N - 1;  // clamp loads; stores guarded below
    const float* xp = x + arow * 128 + q * 8;
    half8 af[4];
#pragma unroll
    for (int s = 0; s < 4; ++s) {
      float4 v0 = *(const float4*)(xp + s * 32);
      float4 v1 = *(const float4*)(xp + s * 32 + 4);
      af[s][0] = (h16)v0.x; af[s][1] = (h16)v0.y;
      af[s][2] = (h16)v0.z; af[s][3] = (h16)v0.w;
      af[s][4] = (h16)v1.x; af[s][5] = (h16)v1.y;
      af[s][6] = (h16)v1.z; af[s][7] = (h16)v1.w;
    }
    f32x4 acc[4] = {{0.f, 0.f, 0.f, 0.f}, {0.f, 0.f, 0.f, 0.f},
                    {0.f, 0.f, 0.f, 0.f}, {0.f, 0.f, 0.f, 0.f}};
#pragma unroll
    for (int s = 0; s < 4; ++s)
#pragma unroll
      for (int t = 0; t < 4; ++t)
        acc[t] = __builtin_amdgcn_mfma_f32_16x16x32_f16(af[s], bf[t][s], acc[t], 0, 0, 0);
#pragma unroll
    for (int t = 0; t < 4; ++t)
#pragma unroll
      for (int rr = 0; rr < 4; ++rr) {
        long long row = row0 + q * 4 + rr;
        if (row < N) h[row * 64 + t * 16 + r16] = (h16)acc[t][rr];
      }
  }
}

// ---------------------------------------------------------------- GEMM2 (MFMA): h[N,64](f16) = in[N,64](f16) @ W[64,64](f32)
__global__ __launch_bounds__(256, 1) void k_gemm2(const h16* __restrict__ xh,
                                                  const float* __restrict__ W,
                                                  h16* __restrict__ h, int N) {
  int lane = threadIdx.x & 63;
  int wave = threadIdx.x >> 6;
  int q = lane >> 4, r16 = lane & 15;
  half8 bf[4][2];
#pragma unroll
  for (int t = 0; t < 4; ++t)
#pragma unroll
    for (int s = 0; s < 2; ++s) {
      const float* wp = W + (s * 32 + q * 8) * 64 + t * 16 + r16;
#pragma unroll
      for (int j = 0; j < 8; ++j) bf[t][s][j] = (h16)wp[j * 64];
    }
  long long base_row = (long long)blockIdx.x * 128 + wave * 32;
#pragma unroll
  for (int rt = 0; rt < 2; ++rt) {
    long long row0 = base_row + rt * 16;
    long long arow = row0 + r16;
    if (arow >= N) arow = N - 1;
    half8 af[2];
#pragma unroll
    for (int s = 0; s < 2; ++s)
      af[s] = *(const half8*)(xh + arow * 64 + s * 32 + q * 8);  // 16B aligned
    f32x4 acc[4] = {{0.f, 0.f, 0.f, 0.f}, {0.f, 0.f, 0.f, 0.f},
                    {0.f, 0.f, 0.f, 0.f}, {0.f, 0.f, 0.f, 0.f}};
#pragma unroll
    for (int s = 0; s < 2; ++s)
#pragma unroll
      for (int t = 0; t < 4; ++t)
        acc[t] = __builtin_amdgcn_mfma_f32_16x16x32_f16(af[s], bf[t][s], acc[t], 0, 0, 0);
#pragma unroll
    for (int t = 0; t < 4; ++t)
#pragma unroll
      for (int rr = 0; rr < 4; ++rr) {
        long long row = row0 + q * 4 + rr;
        if (row < N) h[row * 64 + t * 16 + r16] = (h16)acc[t][rr];
      }
  }
}

// ---------------------------------------------------------------- CSR gather + self-loop + bias + BN + ReLU (fused, fp16 h)
__global__ __launch_bounds__(256) void k_gath(const int* __restrict__ csr,
                                              const int* __restrict__ offs,
                                              const float* __restrict__ dinv,
                                              const h16* __restrict__ hin,
                                              const float* __restrict__ b,
                                              const float* __restrict__ g,
                                              const float* __restrict__ be,
                                              const float* __restrict__ m,
                                              const float* __restrict__ v,
                                              h16* __restrict__ hout, int N) {
  int lane = threadIdx.x & 63;
  int node = (int)(((long long)blockIdx.x * blockDim.x + threadIdx.x) >> 6);
  if (node >= N) return;
  node = __builtin_amdgcn_readfirstlane(node);
  int beg = offs[node], end = offs[node + 1];
  float acc = 0.f;
  int j = beg;
  for (; j + 4 <= end; j += 4) {  // 4 independent row loads in flight
    int s0 = csr[j], s1 = csr[j + 1], s2 = csr[j + 2], s3 = csr[j + 3];
    float w0 = dinv[s0], w1 = dinv[s1], w2 = dinv[s2], w3 = dinv[s3];
    float h0 = (float)hin[(long long)s0 * 64 + lane];
    float h1 = (float)hin[(long long)s1 * 64 + lane];
    float h2 = (float)hin[(long long)s2 * 64 + lane];
    float h3 = (float)hin[(long long)s3 * 64 + lane];
    acc = fmaf(w0, h0, acc);
    acc = fmaf(w1, h1, acc);
    acc = fmaf(w2, h2, acc);
    acc = fmaf(w3, h3, acc);
  }
  for (; j < end; ++j) {
    int s = csr[j];
    acc = fmaf(dinv[s], (float)hin[(long long)s * 64 + lane], acc);
  }
  float di = dinv[node];
  acc = fmaf(di, (float)hin[(long long)node * 64 + lane], acc);  // self-loop
  acc = fmaf(di, acc, b[lane]);                                  // scale + bias
  float A = g[lane] * rsqrtf(v[lane] + EPSV);
  float B = be[lane] - m[lane] * A;
  hout[(long long)node * 64 + lane] = (h16)fmaxf(fmaf(acc, A, B), 0.f);
}

// ---------------------------------------------------------------- MLP head + sigmoid (fp16 input, already BN+ReLU)
__global__ __launch_bounds__(256) void k_cls(const h16* __restrict__ h,
                                             const float* __restrict__ Wc1,
                                             const float* __restrict__ bc1,
                                             const float* __restrict__ Wc2,
                                             const float* __restrict__ bc2,
                                             float* __restrict__ out, int N) {
  __shared__ float sW1[64 * 32];
  __shared__ float sW2[32];
  __shared__ float sb1[32];
  for (int i = threadIdx.x; i < 64 * 32; i += blockDim.x) sW1[i] = Wc1[i];
  if (threadIdx.x < 32) {
    sW2[threadIdx.x] = Wc2[threadIdx.x];
    sb1[threadIdx.x] = bc1[threadIdx.x];
  }
  __syncthreads();
  int node = blockIdx.x * blockDim.x + threadIdx.x;
  if (node >= N) return;
  const uint4* hp = (const uint4*)(h + (long long)node * 64);
  float mid[32];
#pragma unroll
  for (int j = 0; j < 32; ++j) mid[j] = sb1[j];
#pragma unroll
  for (int j4 = 0; j4 < 8; ++j4) {
    uint4 qv = hp[j4];
    unsigned int pk[4] = {qv.x, qv.y, qv.z, qv.w};
#pragma unroll
    for (int c = 0; c < 4; ++c) {
      float f0 = h2f(pk[c] & 0xffffu);
      float f1 = h2f(pk[c] >> 16);
      int f = j4 * 8 + c * 2;
#pragma unroll
      for (int j = 0; j < 32; ++j) mid[j] = fmaf(f0, sW1[f * 32 + j], mid[j]);
#pragma unroll
      for (int j = 0; j < 32; ++j) mid[j] = fmaf(f1, sW1[(f + 1) * 32 + j], mid[j]);
    }
  }
  float o = bc2[0];
#pragma unroll
  for (int j = 0; j < 32; ++j) o = fmaf(fmaxf(mid[j], 0.f), sW2[j], o);
  out[node] = 1.f / (1.f + expf(-o));
}

// ---------------------------------------------------------------- launch
extern "C" void kernel_launch(void* const* d_in, const int* in_sizes, int n_in,
                              void* d_out, int out_size, void* d_ws, size_t ws_size,
                              hipStream_t stream) {
  const float* x  = (const float*)d_in[0];
  const int* ei   = (const int*)d_in[1];
  const float* W1 = (const float*)d_in[2];
  const float* b1 = (const float*)d_in[3];
  const float* g1 = (const float*)d_in[4];
  const float* be1 = (const float*)d_in[5];
  const float* m1 = (const float*)d_in[6];
  const float* v1 = (const float*)d_in[7];
  const float* W2 = (const float*)d_in[8];
  const float* b2 = (const float*)d_in[9];
  const float* g2 = (const float*)d_in[10];
  const float* be2 = (const float*)d_in[11];
  const float* m2 = (const float*)d_in[12];
  const float* v2 = (const float*)d_in[13];
  const float* Wc1 = (const float*)d_in[14];
  const float* bc1 = (const float*)d_in[15];
  const float* Wc2 = (const float*)d_in[16];
  const float* bc2 = (const float*)d_in[17];
  float* out = (float*)d_out;

  int N = in_sizes[0] / 128;
  int E = in_sizes[1] / 2;
  int Npad = ((N + 63) / 64) * 64;
  int nb = (N + 1023) / 1024;

  char* ws = (char*)d_ws;
  h16*   bufA  = (h16*)ws;                              // [N*64] fp16
  h16*   bufB  = bufA + (long long)N * 64;              // [N*64] fp16
  int*   csr   = (int*)(bufB + (long long)N * 64);      // [E]
  float* dinv  = (float*)(csr + E);                     // [Npad]
  int*   cnt   = (int*)(dinv + Npad);                   // [Npad]
  int*   offs  = cnt + Npad;                            // [Npad + 64]
  int*   cursor = offs + Npad + 64;                     // [Npad]
  int*   bsum  = cursor + Npad;                         // [512]
  size_t need = (size_t)((char*)(bsum + 512) - (char*)d_ws);
  if (need > ws_size) return;  // fail loudly rather than corrupt

  // ---- graph preprocessing (CSR build) ----
  k_zero<<<256, 256, 0, stream>>>((int4*)cnt, Npad / 4);
  k_deg<<<(E + 255) / 256, 256, 0, stream>>>(ei, cnt, E);
  k_bsum<<<nb, 256, 0, stream>>>(cnt, bsum, N);
  k_bscan<<<1, 256, 0, stream>>>(bsum, nb, offs + N, E);
  k_scan3<<<nb, 256, 0, stream>>>(cnt, bsum, offs, cursor, dinv, N);
  // dst-windowed scatter: 16384 nodes (~1MB csr window) per pass
  for (int lo = 0; lo < N; lo += 16384)
    k_scat<<<(E + 255) / 256, 256, 0, stream>>>(ei, cursor, csr, E, lo, lo + 16384);

  // ---- layer 1 ----
  k_gemm1<<<(N + 127) / 128, 256, 0, stream>>>(x, W1, bufA, N);
  k_gath<<<(N * 64 + 255) / 256, 256, 0, stream>>>(csr, offs, dinv, bufA,
                                                   b1, g1, be1, m1, v1, bufB, N);
  // ---- layer 2 ----
  k_gemm2<<<(N + 127) / 128, 256, 0, stream>>>(bufB, W2, bufA, N);
  k_gath<<<(N * 64 + 255) / 256, 256, 0, stream>>>(csr, offs, dinv, bufA,
                                                   b2, g2, be2, m2, v2, bufB, N);
  // ---- classifier head ----
  k_cls<<<(N + 255) / 256, 256, 0, stream>>>(bufB, Wc1, bc1, Wc2, bc2, out, N);
}